// Round 1
// baseline (2533.189 us; speedup 1.0000x reference)
//
#include <hip/hip_runtime.h>
#include <math.h>

#define NE 200000
#define NN 25000

static constexpr float INV_SQRT3  = 0.5773502691896258f;
static constexpr float INV_SQRT2  = 0.7071067811865476f;
static constexpr float INV_SQRT8  = 0.3535533905932738f;
static constexpr float INV_SQRT24 = 0.2041241452319315f;

// ---------------- prep: transpose radial weights ----------------
// kW1/vW1: (16,64) -> W1T (64,16) ; kW2/vW2: (64,320) -> W2T (320,64)
__global__ __launch_bounds__(256) void prep_kernel(
    const float* __restrict__ kW1, const float* __restrict__ kW2,
    const float* __restrict__ vW1, const float* __restrict__ vW2,
    float* __restrict__ kW1T, float* __restrict__ vW1T,
    float* __restrict__ kW2T, float* __restrict__ vW2T)
{
  int t = blockIdx.x * blockDim.x + threadIdx.x;
  if (t < 1024) {
    int j = t >> 6;      // 0..15
    int r = t & 63;      // 0..63
    kW1T[r * 16 + j] = kW1[t];
    vW1T[r * 16 + j] = vW1[t];
  }
  if (t < 20480) {
    int r = t / 320;
    int o = t % 320;
    kW2T[o * 64 + r] = kW2[t];
    vW2T[o * 64 + r] = vW2[t];
  }
}

// ---------------- per-node q precompute ----------------
// qd[n][k]     = sum_m (ns@Wq0)[m] * Wd0[m][k] / sqrt(8)
// qvd[n][k][c] = sum_m (nv@Wq1)[m][c] * Wd1[m][k] / sqrt(8)
__global__ __launch_bounds__(256) void node_kernel(
    const float* __restrict__ node_attr,
    const float* __restrict__ Wq0, const float* __restrict__ Wq1,
    const float* __restrict__ Wd0, const float* __restrict__ Wd1,
    float* __restrict__ qd, float* __restrict__ qvd)
{
  int n = blockIdx.x * blockDim.x + threadIdx.x;
  if (n >= NN) return;
  float ns[8], nv[24];
#pragma unroll
  for (int i = 0; i < 8; ++i)  ns[i] = node_attr[n * 32 + i];
#pragma unroll
  for (int i = 0; i < 24; ++i) nv[i] = node_attr[n * 32 + 8 + i];

  float qs[8];
#pragma unroll
  for (int m = 0; m < 8; ++m) {
    float a = 0.f;
#pragma unroll
    for (int i = 0; i < 8; ++i) a = fmaf(ns[i], Wq0[i * 8 + m], a);
    qs[m] = a * INV_SQRT8;
  }
#pragma unroll
  for (int k = 0; k < 8; ++k) {
    float a = 0.f;
#pragma unroll
    for (int m = 0; m < 8; ++m) a = fmaf(qs[m], Wd0[m * 8 + k], a);
    qd[n * 8 + k] = a;
  }

  float qv[24];
#pragma unroll
  for (int k = 0; k < 8; ++k) {
#pragma unroll
    for (int c = 0; c < 3; ++c) {
      float a = 0.f;
#pragma unroll
      for (int m = 0; m < 8; ++m) a = fmaf(nv[m * 3 + c], Wq1[m * 8 + k], a);
      qv[k * 3 + c] = a * INV_SQRT8;
    }
  }
#pragma unroll
  for (int k = 0; k < 8; ++k) {
#pragma unroll
    for (int c = 0; c < 3; ++c) {
      float a = 0.f;
#pragma unroll
      for (int m = 0; m < 8; ++m) a = fmaf(qv[m * 3 + c], Wd1[m * 8 + k], a);
      qvd[n * 24 + k * 3 + c] = a;
    }
  }
}

// ---------------- main edge pass ----------------
// For each edge: radial MLP (both branches) fused with the tensor product.
// b=0: k-branch -> logit -> exp -> atomics into z_sum/cnt, store exp.
// b=1: v-branch -> store v_edge (32 floats).
__global__ __launch_bounds__(256) void edge_kernel(
    const float* __restrict__ node_attr,
    const int*   __restrict__ edge_index,
    const float* __restrict__ edge_attr,
    const float* __restrict__ edge_sh,
    const float* __restrict__ kW1T, const float* __restrict__ kW2T,
    const float* __restrict__ vW1T, const float* __restrict__ vW2T,
    const float* __restrict__ qd,   const float* __restrict__ qvd,
    float* __restrict__ expo, float* __restrict__ v_edge,
    float* __restrict__ z_sum, float* __restrict__ cnt)
{
  int e = blockIdx.x * blockDim.x + threadIdx.x;
  if (e >= NE) return;
  int src = edge_index[e];
  int dst = edge_index[NE + e];

  float ea[16];
#pragma unroll
  for (int j = 0; j < 16; ++j) ea[j] = edge_attr[e * 16 + j];
  float s0  = edge_sh[e * 4 + 0];
  float s1x = edge_sh[e * 4 + 1];
  float s1y = edge_sh[e * 4 + 2];
  float s1z = edge_sh[e * 4 + 3];

  float acc_s[8];
  float acc_v[8][3];

#pragma unroll 1
  for (int b = 0; b < 2; ++b) {
    const float* __restrict__ W1T = b ? vW1T : kW1T;
    const float* __restrict__ W2T = b ? vW2T : kW2T;

    // h = silu(ea @ W1 / 4)
    float h[64];
#pragma unroll
    for (int r = 0; r < 64; ++r) {
      float a = 0.f;
#pragma unroll
      for (int j = 0; j < 16; ++j) a = fmaf(ea[j], W1T[r * 16 + j], a);
      a *= 0.25f;
      h[r] = a / (1.f + __expf(-a));
    }

#pragma unroll
    for (int n = 0; n < 8; ++n) {
      acc_s[n] = 0.f;
      acc_v[n][0] = 0.f; acc_v[n][1] = 0.f; acc_v[n][2] = 0.f;
    }

#pragma unroll 1
    for (int m = 0; m < 8; ++m) {
      float xsm = node_attr[src * 32 + m];
      float xv0 = node_attr[src * 32 + 8 + m * 3 + 0];
      float xv1 = node_attr[src * 32 + 8 + m * 3 + 1];
      float xv2 = node_attr[src * 32 + 8 + m * 3 + 2];

      float dotm = (xv0 * s1x + xv1 * s1y + xv2 * s1z) * INV_SQRT3;
      float crx = (xv1 * s1z - xv2 * s1y) * INV_SQRT2;
      float cry = (xv2 * s1x - xv0 * s1z) * INV_SQRT2;
      float crz = (xv0 * s1y - xv1 * s1x) * INV_SQRT2;
      float gs  = xsm * s0;
      float g1x = xsm * s1x, g1y = xsm * s1y, g1z = xsm * s1z;
      float g20 = xv0 * s0,  g21 = xv1 * s0,  g22 = xv2 * s0;

      const float* __restrict__ base = W2T + m * 8 * 64;  // p=0 rows for this m
#pragma unroll
      for (int n = 0; n < 8; ++n) {
        const float* __restrict__ r0 = base + n * 64;
        float w0 = 0.f, w1 = 0.f, w2 = 0.f, w3 = 0.f, w4 = 0.f;
#pragma unroll
        for (int r = 0; r < 64; ++r) {
          float hr = h[r];
          w0 = fmaf(hr, r0[r],            w0);   // path 0
          w1 = fmaf(hr, r0[r +  64 * 64], w1);   // path 1
          w2 = fmaf(hr, r0[r + 128 * 64], w2);   // path 2
          w3 = fmaf(hr, r0[r + 192 * 64], w3);   // path 3
          w4 = fmaf(hr, r0[r + 256 * 64], w4);   // path 4
        }
        acc_s[n]    += w0 * gs  + w3 * dotm;
        acc_v[n][0] += w1 * g1x + w2 * g20 + w4 * crx;
        acc_v[n][1] += w1 * g1y + w2 * g21 + w4 * cry;
        acc_v[n][2] += w1 * g1z + w2 * g22 + w4 * crz;
      }
    }

    if (b == 0) {
      // logits = (qd . ks + (qvd : kv)/sqrt3) / 4
      // ks = acc_s/32 ; kv = acc_v * (1/8) * INV_SQRT24
      float lg = 0.f, lv = 0.f;
#pragma unroll
      for (int n = 0; n < 8; ++n) lg = fmaf(acc_s[n], qd[dst * 8 + n], lg);
#pragma unroll
      for (int n = 0; n < 8; ++n) {
#pragma unroll
        for (int c = 0; c < 3; ++c)
          lv = fmaf(acc_v[n][c], qvd[dst * 24 + n * 3 + c], lv);
      }
      float logit = (lg * (1.f / 32.f) +
                     lv * (0.125f * INV_SQRT24) * INV_SQRT3) * 0.25f;
      float ex = __expf(logit);
      expo[e] = ex;
      atomicAdd(&z_sum[dst], ex);
      atomicAdd(&cnt[dst], 1.f);
    } else {
#pragma unroll
      for (int n = 0; n < 8; ++n)
        v_edge[e * 32 + n] = acc_s[n] * (1.f / 32.f);
#pragma unroll
      for (int n = 0; n < 8; ++n) {
#pragma unroll
        for (int c = 0; c < 3; ++c)
          v_edge[e * 32 + 8 + n * 3 + c] = acc_v[n][c] * (0.125f * INV_SQRT24);
      }
    }
  }
}

// ---------------- z = z_sum / max(cnt,1) ----------------
__global__ __launch_bounds__(256) void zdiv_kernel(float* __restrict__ z_sum,
                                                   const float* __restrict__ cnt)
{
  int n = blockIdx.x * blockDim.x + threadIdx.x;
  if (n >= NN) return;
  z_sum[n] = z_sum[n] / fmaxf(cnt[n], 1.f);
}

// ---------------- scatter: out[dst] += sqrt(relu(exp/z[dst])) * v_edge ----------------
__global__ __launch_bounds__(256) void scatter_kernel(
    const int*   __restrict__ edge_index,
    const float* __restrict__ expo,
    const float* __restrict__ z,
    const float* __restrict__ v_edge,
    float* __restrict__ out)
{
  int t = blockIdx.x * blockDim.x + threadIdx.x;
  if (t >= NE * 8) return;
  int e = t >> 3;
  int q = t & 7;
  int dst = edge_index[NE + e];
  float a = sqrtf(fmaxf(expo[e] / z[dst], 0.f));
  const float4* v4 = (const float4*)v_edge;
  float4 v = v4[e * 8 + q];
  atomicAdd(&out[dst * 32 + q * 4 + 0], a * v.x);
  atomicAdd(&out[dst * 32 + q * 4 + 1], a * v.y);
  atomicAdd(&out[dst * 32 + q * 4 + 2], a * v.z);
  atomicAdd(&out[dst * 32 + q * 4 + 3], a * v.w);
}

extern "C" void kernel_launch(void* const* d_in, const int* in_sizes, int n_in,
                              void* d_out, int out_size, void* d_ws, size_t ws_size,
                              hipStream_t stream)
{
  const float* node_attr  = (const float*)d_in[0];
  const int*   edge_index = (const int*)  d_in[1];
  const float* edge_attr  = (const float*)d_in[2];
  const float* edge_sh    = (const float*)d_in[3];
  const float* Wq0 = (const float*)d_in[4];
  const float* Wq1 = (const float*)d_in[5];
  const float* kW1 = (const float*)d_in[6];
  const float* kW2 = (const float*)d_in[7];
  const float* vW1 = (const float*)d_in[8];
  const float* vW2 = (const float*)d_in[9];
  const float* Wd0 = (const float*)d_in[10];
  const float* Wd1 = (const float*)d_in[11];
  float* out = (float*)d_out;

  float* ws = (float*)d_ws;
  float* qd     = ws;                 // 200000
  float* qvd    = qd     + 200000;    // 600000
  float* kW1T   = qvd    + 600000;    // 1024
  float* vW1T   = kW1T   + 1024;      // 1024
  float* kW2T   = vW1T   + 1024;      // 20480
  float* vW2T   = kW2T   + 20480;     // 20480
  float* z_sum  = vW2T   + 20480;     // 25024
  float* cnt    = z_sum  + 25024;     // 25024
  float* expo   = cnt    + 25024;     // 200000
  float* v_edge = expo   + 200000;    // 6400000
  // total ~29.97 MB

  hipMemsetAsync(out, 0, (size_t)out_size * sizeof(float), stream);
  hipMemsetAsync(z_sum, 0, (size_t)(25024 + 25024) * sizeof(float), stream);

  prep_kernel<<<(20480 + 255) / 256, 256, 0, stream>>>(
      kW1, kW2, vW1, vW2, kW1T, vW1T, kW2T, vW2T);
  node_kernel<<<(NN + 255) / 256, 256, 0, stream>>>(
      node_attr, Wq0, Wq1, Wd0, Wd1, qd, qvd);
  edge_kernel<<<(NE + 255) / 256, 256, 0, stream>>>(
      node_attr, edge_index, edge_attr, edge_sh,
      kW1T, kW2T, vW1T, vW2T, qd, qvd, expo, v_edge, z_sum, cnt);
  zdiv_kernel<<<(NN + 255) / 256, 256, 0, stream>>>(z_sum, cnt);
  scatter_kernel<<<(NE * 8 + 255) / 256, 256, 0, stream>>>(
      edge_index, expo, z_sum, v_edge, out);
}

// Round 2
// 977.422 us; speedup vs baseline: 2.5917x; 2.5917x over previous
//
#include <hip/hip_runtime.h>
#include <math.h>

#define NE 200000
#define NN 25000

static constexpr float INV_SQRT3  = 0.5773502691896258f;
static constexpr float INV_SQRT2  = 0.7071067811865476f;
static constexpr float INV_SQRT8  = 0.3535533905932738f;
static constexpr float INV_SQRT24 = 0.2041241452319315f;

// ---------------- prep: transpose radial weights ----------------
// kW1/vW1: (16,64) -> W1T (64,16) ; kW2/vW2: (64,320) -> W2T (320,64)
__global__ __launch_bounds__(256) void prep_kernel(
    const float* __restrict__ kW1, const float* __restrict__ kW2,
    const float* __restrict__ vW1, const float* __restrict__ vW2,
    float* __restrict__ kW1T, float* __restrict__ vW1T,
    float* __restrict__ kW2T, float* __restrict__ vW2T)
{
  int t = blockIdx.x * blockDim.x + threadIdx.x;
  if (t < 1024) {
    int j = t >> 6;      // 0..15
    int r = t & 63;      // 0..63
    kW1T[r * 16 + j] = kW1[t];
    vW1T[r * 16 + j] = vW1[t];
  }
  if (t < 20480) {
    int r = t / 320;
    int o = t % 320;
    kW2T[o * 64 + r] = kW2[t];
    vW2T[o * 64 + r] = vW2[t];
  }
}

// ---------------- per-node q precompute ----------------
__global__ __launch_bounds__(256) void node_kernel(
    const float* __restrict__ node_attr,
    const float* __restrict__ Wq0, const float* __restrict__ Wq1,
    const float* __restrict__ Wd0, const float* __restrict__ Wd1,
    float* __restrict__ qd, float* __restrict__ qvd)
{
  int n = blockIdx.x * blockDim.x + threadIdx.x;
  if (n >= NN) return;
  float ns[8], nv[24];
#pragma unroll
  for (int i = 0; i < 8; ++i)  ns[i] = node_attr[n * 32 + i];
#pragma unroll
  for (int i = 0; i < 24; ++i) nv[i] = node_attr[n * 32 + 8 + i];

  float qs[8];
#pragma unroll
  for (int m = 0; m < 8; ++m) {
    float a = 0.f;
#pragma unroll
    for (int i = 0; i < 8; ++i) a = fmaf(ns[i], Wq0[i * 8 + m], a);
    qs[m] = a * INV_SQRT8;
  }
#pragma unroll
  for (int k = 0; k < 8; ++k) {
    float a = 0.f;
#pragma unroll
    for (int m = 0; m < 8; ++m) a = fmaf(qs[m], Wd0[m * 8 + k], a);
    qd[n * 8 + k] = a;
  }

  float qv[24];
#pragma unroll
  for (int k = 0; k < 8; ++k) {
#pragma unroll
    for (int c = 0; c < 3; ++c) {
      float a = 0.f;
#pragma unroll
      for (int m = 0; m < 8; ++m) a = fmaf(nv[m * 3 + c], Wq1[m * 8 + k], a);
      qv[k * 3 + c] = a * INV_SQRT8;
    }
  }
#pragma unroll
  for (int k = 0; k < 8; ++k) {
#pragma unroll
    for (int c = 0; c < 3; ++c) {
      float a = 0.f;
#pragma unroll
      for (int m = 0; m < 8; ++m) a = fmaf(qv[m * 3 + c], Wd1[m * 8 + k], a);
      qvd[n * 24 + k * 3 + c] = a;
    }
  }
}

// 64-long dot of h (registers) against one LDS weight row (wave-uniform
// address -> broadcast ds_read_b128, conflict-free). 4 independent FMA chains.
__device__ __forceinline__ float dot64(const float* __restrict__ s, const float (&h)[64])
{
  const float4* a4 = (const float4*)s;
  float a0 = 0.f, a1 = 0.f, a2 = 0.f, a3 = 0.f;
#pragma unroll
  for (int q = 0; q < 16; q += 4) {
    float4 v0 = a4[q], v1 = a4[q + 1], v2 = a4[q + 2], v3 = a4[q + 3];
    a0 = fmaf(h[4*q+ 0], v0.x, a0); a0 = fmaf(h[4*q+ 1], v0.y, a0);
    a0 = fmaf(h[4*q+ 2], v0.z, a0); a0 = fmaf(h[4*q+ 3], v0.w, a0);
    a1 = fmaf(h[4*q+ 4], v1.x, a1); a1 = fmaf(h[4*q+ 5], v1.y, a1);
    a1 = fmaf(h[4*q+ 6], v1.z, a1); a1 = fmaf(h[4*q+ 7], v1.w, a1);
    a2 = fmaf(h[4*q+ 8], v2.x, a2); a2 = fmaf(h[4*q+ 9], v2.y, a2);
    a2 = fmaf(h[4*q+10], v2.z, a2); a2 = fmaf(h[4*q+11], v2.w, a2);
    a3 = fmaf(h[4*q+12], v3.x, a3); a3 = fmaf(h[4*q+13], v3.y, a3);
    a3 = fmaf(h[4*q+14], v3.z, a3); a3 = fmaf(h[4*q+15], v3.w, a3);
  }
  return (a0 + a1) + (a2 + a3);
}

// ---------------- main edge pass ----------------
// Per block: 256 edges. W2 is staged into LDS one path (16 KB) at a time and
// read via wave-uniform broadcast. Per-edge node values live in LDS in
// transposed [c][tid] layout (lane-contiguous -> bank-conflict-free) so the
// rolled m-loop doesn't index register arrays dynamically.
__global__ __launch_bounds__(256, 2) void edge_kernel(
    const float* __restrict__ node_attr,
    const int*   __restrict__ edge_index,
    const float* __restrict__ edge_attr,
    const float* __restrict__ edge_sh,
    const float* __restrict__ kW1T, const float* __restrict__ kW2T,
    const float* __restrict__ vW1T, const float* __restrict__ vW2T,
    const float* __restrict__ qd,   const float* __restrict__ qvd,
    float* __restrict__ expo, float* __restrict__ v_edge,
    float* __restrict__ z_sum, float* __restrict__ cnt)
{
  __shared__ float sW[4096];      // 16 KB: one W2 path (or W1T in first 1K)
  __shared__ float sX[32 * 256];  // 32 KB: node values, [c][tid]

  const int tid = threadIdx.x;
  const int e   = blockIdx.x * 256 + tid;
  const bool valid = (e < NE);
  const int el  = valid ? e : (NE - 1);
  const int src = edge_index[el];
  const int dst = edge_index[NE + el];

  // gather this edge's source-node row into LDS (transposed)
  {
    const float4* na4 = (const float4*)(node_attr + (size_t)src * 32);
#pragma unroll
    for (int i = 0; i < 8; ++i) {
      float4 v = na4[i];
      sX[(4*i + 0) * 256 + tid] = v.x;
      sX[(4*i + 1) * 256 + tid] = v.y;
      sX[(4*i + 2) * 256 + tid] = v.z;
      sX[(4*i + 3) * 256 + tid] = v.w;
    }
  }

  const float s0  = edge_sh[el * 4 + 0];
  const float s1x = edge_sh[el * 4 + 1];
  const float s1y = edge_sh[el * 4 + 2];
  const float s1z = edge_sh[el * 4 + 3];

  float ea[16];
  {
    const float4* ea4 = (const float4*)(edge_attr + (size_t)el * 16);
#pragma unroll
    for (int i = 0; i < 4; ++i) {
      float4 v = ea4[i];
      ea[4*i+0] = v.x; ea[4*i+1] = v.y; ea[4*i+2] = v.z; ea[4*i+3] = v.w;
    }
  }

#pragma unroll 1
  for (int b = 0; b < 2; ++b) {
    const float* __restrict__ W1T = b ? vW1T : kW1T;
    const float* __restrict__ W2T = b ? vW2T : kW2T;

    // ---- stage W1T, compute h = silu(ea @ W1 / 4) ----
    __syncthreads();
    if (tid < 256) ((float4*)sW)[tid] = ((const float4*)W1T)[tid];
    __syncthreads();

    float h[64];
#pragma unroll
    for (int r = 0; r < 64; ++r) {
      const float4* row = (const float4*)(sW + r * 16);
      float4 x0 = row[0], x1 = row[1], x2 = row[2], x3 = row[3];
      float a0 = 0.f, a1 = 0.f;
      a0 = fmaf(ea[ 0], x0.x, a0); a0 = fmaf(ea[ 1], x0.y, a0);
      a0 = fmaf(ea[ 2], x0.z, a0); a0 = fmaf(ea[ 3], x0.w, a0);
      a1 = fmaf(ea[ 4], x1.x, a1); a1 = fmaf(ea[ 5], x1.y, a1);
      a1 = fmaf(ea[ 6], x1.z, a1); a1 = fmaf(ea[ 7], x1.w, a1);
      a0 = fmaf(ea[ 8], x2.x, a0); a0 = fmaf(ea[ 9], x2.y, a0);
      a0 = fmaf(ea[10], x2.z, a0); a0 = fmaf(ea[11], x2.w, a0);
      a1 = fmaf(ea[12], x3.x, a1); a1 = fmaf(ea[13], x3.y, a1);
      a1 = fmaf(ea[14], x3.z, a1); a1 = fmaf(ea[15], x3.w, a1);
      float a = (a0 + a1) * 0.25f;
      h[r] = a / (1.f + __expf(-a));
    }

    float acc_s[8];
    float acc_v[8][3];
#pragma unroll
    for (int n = 0; n < 8; ++n) {
      acc_s[n] = 0.f;
      acc_v[n][0] = 0.f; acc_v[n][1] = 0.f; acc_v[n][2] = 0.f;
    }

    // ---- path 0: acc_s[n] += w * (xs_m * s0) ----
    __syncthreads();
#pragma unroll
    for (int i = 0; i < 4; ++i) ((float4*)sW)[tid + 256*i] = ((const float4*)(W2T + 0*4096))[tid + 256*i];
    __syncthreads();
#pragma unroll 1
    for (int m = 0; m < 8; ++m) {
      float g = sX[m * 256 + tid] * s0;
      const float* base = sW + m * 512;
#pragma unroll
      for (int n = 0; n < 8; ++n)
        acc_s[n] = fmaf(dot64(base + n * 64, h), g, acc_s[n]);
    }

    // ---- path 3: acc_s[n] += w * dot_m ----
    __syncthreads();
#pragma unroll
    for (int i = 0; i < 4; ++i) ((float4*)sW)[tid + 256*i] = ((const float4*)(W2T + 3*4096))[tid + 256*i];
    __syncthreads();
#pragma unroll 1
    for (int m = 0; m < 8; ++m) {
      float x0 = sX[(8 + 3*m + 0) * 256 + tid];
      float x1 = sX[(8 + 3*m + 1) * 256 + tid];
      float x2 = sX[(8 + 3*m + 2) * 256 + tid];
      float dm = (x0 * s1x + x1 * s1y + x2 * s1z) * INV_SQRT3;
      const float* base = sW + m * 512;
#pragma unroll
      for (int n = 0; n < 8; ++n)
        acc_s[n] = fmaf(dot64(base + n * 64, h), dm, acc_s[n]);
    }

    // ---- path 1: acc_v[n][c] += w * (xs_m * s1c) ----
    __syncthreads();
#pragma unroll
    for (int i = 0; i < 4; ++i) ((float4*)sW)[tid + 256*i] = ((const float4*)(W2T + 1*4096))[tid + 256*i];
    __syncthreads();
#pragma unroll 1
    for (int m = 0; m < 8; ++m) {
      float xsm = sX[m * 256 + tid];
      float g1x = xsm * s1x, g1y = xsm * s1y, g1z = xsm * s1z;
      const float* base = sW + m * 512;
#pragma unroll
      for (int n = 0; n < 8; ++n) {
        float w = dot64(base + n * 64, h);
        acc_v[n][0] = fmaf(w, g1x, acc_v[n][0]);
        acc_v[n][1] = fmaf(w, g1y, acc_v[n][1]);
        acc_v[n][2] = fmaf(w, g1z, acc_v[n][2]);
      }
    }

    // ---- path 2: acc_v[n][c] += w * (xv_mc * s0) ----
    __syncthreads();
#pragma unroll
    for (int i = 0; i < 4; ++i) ((float4*)sW)[tid + 256*i] = ((const float4*)(W2T + 2*4096))[tid + 256*i];
    __syncthreads();
#pragma unroll 1
    for (int m = 0; m < 8; ++m) {
      float g20 = sX[(8 + 3*m + 0) * 256 + tid] * s0;
      float g21 = sX[(8 + 3*m + 1) * 256 + tid] * s0;
      float g22 = sX[(8 + 3*m + 2) * 256 + tid] * s0;
      const float* base = sW + m * 512;
#pragma unroll
      for (int n = 0; n < 8; ++n) {
        float w = dot64(base + n * 64, h);
        acc_v[n][0] = fmaf(w, g20, acc_v[n][0]);
        acc_v[n][1] = fmaf(w, g21, acc_v[n][1]);
        acc_v[n][2] = fmaf(w, g22, acc_v[n][2]);
      }
    }

    // ---- path 4: acc_v[n][c] += w * cross_mc ----
    __syncthreads();
#pragma unroll
    for (int i = 0; i < 4; ++i) ((float4*)sW)[tid + 256*i] = ((const float4*)(W2T + 4*4096))[tid + 256*i];
    __syncthreads();
#pragma unroll 1
    for (int m = 0; m < 8; ++m) {
      float x0 = sX[(8 + 3*m + 0) * 256 + tid];
      float x1 = sX[(8 + 3*m + 1) * 256 + tid];
      float x2 = sX[(8 + 3*m + 2) * 256 + tid];
      float crx = (x1 * s1z - x2 * s1y) * INV_SQRT2;
      float cry = (x2 * s1x - x0 * s1z) * INV_SQRT2;
      float crz = (x0 * s1y - x1 * s1x) * INV_SQRT2;
      const float* base = sW + m * 512;
#pragma unroll
      for (int n = 0; n < 8; ++n) {
        float w = dot64(base + n * 64, h);
        acc_v[n][0] = fmaf(w, crx, acc_v[n][0]);
        acc_v[n][1] = fmaf(w, cry, acc_v[n][1]);
        acc_v[n][2] = fmaf(w, crz, acc_v[n][2]);
      }
    }

    // ---- epilogue ----
    if (b == 0) {
      float lg = 0.f, lv = 0.f;
#pragma unroll
      for (int n = 0; n < 8; ++n) lg = fmaf(acc_s[n], qd[dst * 8 + n], lg);
#pragma unroll
      for (int n = 0; n < 8; ++n) {
#pragma unroll
        for (int c = 0; c < 3; ++c)
          lv = fmaf(acc_v[n][c], qvd[dst * 24 + n * 3 + c], lv);
      }
      float logit = (lg * (1.f / 32.f) +
                     lv * (0.125f * INV_SQRT24) * INV_SQRT3) * 0.25f;
      float ex = __expf(logit);
      if (valid) {
        expo[e] = ex;
        atomicAdd(&z_sum[dst], ex);
        atomicAdd(&cnt[dst], 1.f);
      }
    } else {
      if (valid) {
        float4* v4 = (float4*)(v_edge + (size_t)e * 32);
        float4 o;
        o.x = acc_s[0] * (1.f/32.f); o.y = acc_s[1] * (1.f/32.f);
        o.z = acc_s[2] * (1.f/32.f); o.w = acc_s[3] * (1.f/32.f);
        v4[0] = o;
        o.x = acc_s[4] * (1.f/32.f); o.y = acc_s[5] * (1.f/32.f);
        o.z = acc_s[6] * (1.f/32.f); o.w = acc_s[7] * (1.f/32.f);
        v4[1] = o;
        const float sv = 0.125f * INV_SQRT24;
        float vv[24];
#pragma unroll
        for (int n = 0; n < 8; ++n) {
          vv[3*n+0] = acc_v[n][0] * sv;
          vv[3*n+1] = acc_v[n][1] * sv;
          vv[3*n+2] = acc_v[n][2] * sv;
        }
#pragma unroll
        for (int i = 0; i < 6; ++i) {
          float4 t;
          t.x = vv[4*i+0]; t.y = vv[4*i+1]; t.z = vv[4*i+2]; t.w = vv[4*i+3];
          v4[2 + i] = t;
        }
      }
    }
  }
}

// ---------------- zinv = max(cnt,1) / z_sum ----------------
__global__ __launch_bounds__(256) void zdiv_kernel(float* __restrict__ z_sum,
                                                   const float* __restrict__ cnt)
{
  int n = blockIdx.x * blockDim.x + threadIdx.x;
  if (n >= NN) return;
  z_sum[n] = fmaxf(cnt[n], 1.f) / z_sum[n];
}

// ---------------- scatter: out[dst] += sqrt(exp*zinv[dst]) * v_edge ----------------
__global__ __launch_bounds__(256) void scatter_kernel(
    const int*   __restrict__ edge_index,
    const float* __restrict__ expo,
    const float* __restrict__ zinv,
    const float* __restrict__ v_edge,
    float* __restrict__ out)
{
  int t = blockIdx.x * blockDim.x + threadIdx.x;
  if (t >= NE * 8) return;
  int e = t >> 3;
  int q = t & 7;
  int dst = edge_index[NE + e];
  float a = sqrtf(fmaxf(expo[e] * zinv[dst], 0.f));
  const float4* v4 = (const float4*)v_edge;
  float4 v = v4[e * 8 + q];
  atomicAdd(&out[dst * 32 + q * 4 + 0], a * v.x);
  atomicAdd(&out[dst * 32 + q * 4 + 1], a * v.y);
  atomicAdd(&out[dst * 32 + q * 4 + 2], a * v.z);
  atomicAdd(&out[dst * 32 + q * 4 + 3], a * v.w);
}

extern "C" void kernel_launch(void* const* d_in, const int* in_sizes, int n_in,
                              void* d_out, int out_size, void* d_ws, size_t ws_size,
                              hipStream_t stream)
{
  const float* node_attr  = (const float*)d_in[0];
  const int*   edge_index = (const int*)  d_in[1];
  const float* edge_attr  = (const float*)d_in[2];
  const float* edge_sh    = (const float*)d_in[3];
  const float* Wq0 = (const float*)d_in[4];
  const float* Wq1 = (const float*)d_in[5];
  const float* kW1 = (const float*)d_in[6];
  const float* kW2 = (const float*)d_in[7];
  const float* vW1 = (const float*)d_in[8];
  const float* vW2 = (const float*)d_in[9];
  const float* Wd0 = (const float*)d_in[10];
  const float* Wd1 = (const float*)d_in[11];
  float* out = (float*)d_out;

  float* ws = (float*)d_ws;
  float* qd     = ws;                 // 200000
  float* qvd    = qd     + 200000;    // 600000
  float* kW1T   = qvd    + 600000;    // 1024
  float* vW1T   = kW1T   + 1024;      // 1024
  float* kW2T   = vW1T   + 1024;      // 20480
  float* vW2T   = kW2T   + 20480;     // 20480
  float* z_sum  = vW2T   + 20480;     // 25024
  float* cnt    = z_sum  + 25024;     // 25024
  float* expo   = cnt    + 25024;     // 200000
  float* v_edge = expo   + 200000;    // 6400000

  hipMemsetAsync(out, 0, (size_t)out_size * sizeof(float), stream);
  hipMemsetAsync(z_sum, 0, (size_t)(25024 + 25024) * sizeof(float), stream);

  prep_kernel<<<(20480 + 255) / 256, 256, 0, stream>>>(
      kW1, kW2, vW1, vW2, kW1T, vW1T, kW2T, vW2T);
  node_kernel<<<(NN + 255) / 256, 256, 0, stream>>>(
      node_attr, Wq0, Wq1, Wd0, Wd1, qd, qvd);
  edge_kernel<<<(NE + 255) / 256, 256, 0, stream>>>(
      node_attr, edge_index, edge_attr, edge_sh,
      kW1T, kW2T, vW1T, vW2T, qd, qvd, expo, v_edge, z_sum, cnt);
  zdiv_kernel<<<(NN + 255) / 256, 256, 0, stream>>>(z_sum, cnt);
  scatter_kernel<<<(NE * 8 + 255) / 256, 256, 0, stream>>>(
      edge_index, expo, z_sum, v_edge, out);
}

// Round 3
// 351.513 us; speedup vs baseline: 7.2065x; 2.7806x over previous
//
#include <hip/hip_runtime.h>
#include <math.h>

#define NE 200000
#define NN 25000

static constexpr float INV_SQRT3  = 0.5773502691896258f;
static constexpr float INV_SQRT2  = 0.7071067811865476f;
static constexpr float INV_SQRT8  = 0.3535533905932738f;
static constexpr float INV_SQRT24 = 0.2041241452319315f;

typedef __attribute__((ext_vector_type(8))) short bf16x8;
typedef __attribute__((ext_vector_type(4))) float f32x4;

union U16x8 { uint4 u; bf16x8 v; };

__device__ __forceinline__ unsigned f2bf1(float f) {
  unsigned u = __float_as_uint(f);
  return (u + 0x7FFFu + ((u >> 16) & 1u)) >> 16;
}
__device__ __forceinline__ unsigned packbf(float a, float b) {
  return f2bf1(a) | (f2bf1(b) << 16);
}
__device__ __forceinline__ float bflo(unsigned u) { return __uint_as_float(u << 16); }
__device__ __forceinline__ float bfhi(unsigned u) { return __uint_as_float(u & 0xFFFF0000u); }

// ---------------- prep ----------------
// W1T transpose (fp32) + W2 pre-fragmented into MFMA A-operand layout (bf16).
// A-frag for chunk ci (= b*10 + p*2 + half), tile ot, k-step kk, lane L, elem j:
//   A[m = ot*16 + (L&15)][k = kk*32 + (L>>4)*8 + j] of the 32x64 half-chunk
//   = W2[r = k][o = p*64 + half*32 + m]   (orig layout (64 r, 320 o))
__global__ __launch_bounds__(256) void prep_kernel(
    const float* __restrict__ kW1, const float* __restrict__ kW2,
    const float* __restrict__ vW1, const float* __restrict__ vW2,
    float* __restrict__ kW1T, float* __restrict__ vW1T,
    unsigned short* __restrict__ afrag)
{
  int t = blockIdx.x * blockDim.x + threadIdx.x;
  if (t < 1024) {
    int j = t >> 6;      // 0..15
    int r = t & 63;      // 0..63
    kW1T[r * 16 + j] = kW1[t];
    vW1T[r * 16 + j] = vW1[t];
  }
  if (t < 40960) {
    int j    = t & 7;
    int lane = (t >> 3) & 63;
    int kk   = (t >> 9) & 1;
    int ot   = (t >> 10) & 1;
    int ci   = t >> 11;           // 0..19
    int b    = ci / 10;
    int rem  = ci - b * 10;
    int p    = rem >> 1;
    int hf   = rem & 1;
    int r    = kk * 32 + ((lane >> 4) << 3) + j;
    int o    = p * 64 + hf * 32 + ot * 16 + (lane & 15);
    const float* W = b ? vW2 : kW2;
    afrag[t] = (unsigned short)f2bf1(W[r * 320 + o]);
  }
}

// ---------------- per-node q precompute ----------------
__global__ __launch_bounds__(256) void node_kernel(
    const float* __restrict__ node_attr,
    const float* __restrict__ Wq0, const float* __restrict__ Wq1,
    const float* __restrict__ Wd0, const float* __restrict__ Wd1,
    float* __restrict__ qd, float* __restrict__ qvd)
{
  int n = blockIdx.x * blockDim.x + threadIdx.x;
  if (n >= NN) return;
  float ns[8], nv[24];
#pragma unroll
  for (int i = 0; i < 8; ++i)  ns[i] = node_attr[n * 32 + i];
#pragma unroll
  for (int i = 0; i < 24; ++i) nv[i] = node_attr[n * 32 + 8 + i];

  float qs[8];
#pragma unroll
  for (int m = 0; m < 8; ++m) {
    float a = 0.f;
#pragma unroll
    for (int i = 0; i < 8; ++i) a = fmaf(ns[i], Wq0[i * 8 + m], a);
    qs[m] = a * INV_SQRT8;
  }
#pragma unroll
  for (int k = 0; k < 8; ++k) {
    float a = 0.f;
#pragma unroll
    for (int m = 0; m < 8; ++m) a = fmaf(qs[m], Wd0[m * 8 + k], a);
    qd[n * 8 + k] = a;
  }
  float qv[24];
#pragma unroll
  for (int k = 0; k < 8; ++k) {
#pragma unroll
    for (int c = 0; c < 3; ++c) {
      float a = 0.f;
#pragma unroll
      for (int m = 0; m < 8; ++m) a = fmaf(nv[m * 3 + c], Wq1[m * 8 + k], a);
      qv[k * 3 + c] = a * INV_SQRT8;
    }
  }
#pragma unroll
  for (int k = 0; k < 8; ++k) {
#pragma unroll
    for (int c = 0; c < 3; ++c) {
      float a = 0.f;
#pragma unroll
      for (int m = 0; m < 8; ++m) a = fmaf(qv[m * 3 + c], Wd1[m * 8 + k], a);
      qvd[n * 24 + k * 3 + c] = a;
    }
  }
}

// ---------------- main edge pass (MFMA) ----------------
// Per block: 256 edges, 4 waves x 64 edges. Per wave, per branch:
//  1. h[64] per lane (VALU, W1T broadcast from LDS)
//  2. h -> bf16 -> per-wave LDS region sh[e][r] (stride 144 B)
//  3. B-frags (8) read once into regs
//  4. 10 half-chunks: A-frags from global (prefragmented, L2), 16 MFMA,
//     C (32x64 w-chunk) -> per-wave LDS sw[e][o] bf16 (stride 80 B),
//     per-lane contraction into acc_s/acc_v.
// No __syncthreads after W1 staging: all LDS regions are wave-private.
__global__ __launch_bounds__(256, 2) void edge_kernel(
    const float* __restrict__ node_attr,
    const int*   __restrict__ edge_index,
    const float* __restrict__ edge_attr,
    const float* __restrict__ edge_sh,
    const float* __restrict__ kW1T, const float* __restrict__ vW1T,
    const unsigned short* __restrict__ afrag,
    const float* __restrict__ qd,   const float* __restrict__ qvd,
    float* __restrict__ expo, float* __restrict__ v_edge,
    float* __restrict__ z_sum, float* __restrict__ cnt)
{
  __shared__ unsigned char smem[65536];
  float* sW1 = (float*)smem;                              // 8 KiB
  const int tid  = threadIdx.x;
  const int lane = tid & 63;
  const int wave = tid >> 6;
  const int l15  = lane & 15;
  const int quad = lane >> 4;
  unsigned char* sh  = smem + 8192  + wave * 9216;        // 64 x 144 B
  unsigned char* swp = smem + 45056 + wave * 5120;        // 64 x 80 B

  // stage both W1T (2048 floats)
  ((float4*)sW1)[tid]       = ((const float4*)kW1T)[tid];
  ((float4*)sW1)[256 + tid] = ((const float4*)vW1T)[tid];
  __syncthreads();

  const int e = blockIdx.x * 256 + tid;
  const bool valid = (e < NE);
  const int el  = valid ? e : (NE - 1);
  const int src = edge_index[el];
  const int dst = edge_index[NE + el];

  const float s0  = edge_sh[el * 4 + 0];
  const float s1x = edge_sh[el * 4 + 1];
  const float s1y = edge_sh[el * 4 + 2];
  const float s1z = edge_sh[el * 4 + 3];

  float ea[16];
  {
    const float4* ea4 = (const float4*)(edge_attr + (size_t)el * 16);
#pragma unroll
    for (int i = 0; i < 4; ++i) {
      float4 v = ea4[i];
      ea[4*i+0] = v.x; ea[4*i+1] = v.y; ea[4*i+2] = v.z; ea[4*i+3] = v.w;
    }
  }
  float xs[8], xv[8][3];
  {
    const float4* na4 = (const float4*)(node_attr + (size_t)src * 32);
    float tmp[32];
#pragma unroll
    for (int i = 0; i < 8; ++i) {
      float4 v = na4[i];
      tmp[4*i+0] = v.x; tmp[4*i+1] = v.y; tmp[4*i+2] = v.z; tmp[4*i+3] = v.w;
    }
#pragma unroll
    for (int m = 0; m < 8; ++m) xs[m] = tmp[m];
#pragma unroll
    for (int m = 0; m < 8; ++m) {
      xv[m][0] = tmp[8 + 3*m + 0];
      xv[m][1] = tmp[8 + 3*m + 1];
      xv[m][2] = tmp[8 + 3*m + 2];
    }
  }

  const uint4* AF = (const uint4*)afrag;

#pragma unroll 1
  for (int b = 0; b < 2; ++b) {
    // ---- h = silu(ea @ W1 / 4) ----
    const float* W1base = sW1 + b * 1024;
    float h[64];
#pragma unroll
    for (int r = 0; r < 64; ++r) {
      const float4* rp = (const float4*)(W1base + r * 16);
      float4 x0 = rp[0], x1 = rp[1], x2 = rp[2], x3 = rp[3];
      float a0 = 0.f, a1 = 0.f;
      a0 = fmaf(ea[ 0], x0.x, a0); a0 = fmaf(ea[ 1], x0.y, a0);
      a0 = fmaf(ea[ 2], x0.z, a0); a0 = fmaf(ea[ 3], x0.w, a0);
      a1 = fmaf(ea[ 4], x1.x, a1); a1 = fmaf(ea[ 5], x1.y, a1);
      a1 = fmaf(ea[ 6], x1.z, a1); a1 = fmaf(ea[ 7], x1.w, a1);
      a0 = fmaf(ea[ 8], x2.x, a0); a0 = fmaf(ea[ 9], x2.y, a0);
      a0 = fmaf(ea[10], x2.z, a0); a0 = fmaf(ea[11], x2.w, a0);
      a1 = fmaf(ea[12], x3.x, a1); a1 = fmaf(ea[13], x3.y, a1);
      a1 = fmaf(ea[14], x3.z, a1); a1 = fmaf(ea[15], x3.w, a1);
      float a = (a0 + a1) * 0.25f;
      h[r] = a / (1.f + __expf(-a));
    }

    // ---- h -> bf16 -> sh[lane][.] ----
    {
      unsigned char* myrow = sh + lane * 144;
#pragma unroll
      for (int i = 0; i < 8; ++i) {
        uint4 pk;
        pk.x = packbf(h[8*i+0], h[8*i+1]);
        pk.y = packbf(h[8*i+2], h[8*i+3]);
        pk.z = packbf(h[8*i+4], h[8*i+5]);
        pk.w = packbf(h[8*i+6], h[8*i+7]);
        *(uint4*)(myrow + i * 16) = pk;
      }
    }

    // ---- B-fragments (H), read once, reused for all 10 chunks ----
    // B[k = kk*32 + quad*8 + j][n = et*16 + l15] = h_{edge et*16+l15}[k]
    bf16x8 B[4][2];
#pragma unroll
    for (int et = 0; et < 4; ++et) {
#pragma unroll
      for (int kk = 0; kk < 2; ++kk) {
        U16x8 cv;
        cv.u = *(const uint4*)(sh + (et*16 + l15) * 144 + kk * 64 + quad * 16);
        B[et][kk] = cv.v;
      }
    }

    float accs[8];
    float accv[8][3];
#pragma unroll
    for (int n = 0; n < 8; ++n) {
      accs[n] = 0.f;
      accv[n][0] = 0.f; accv[n][1] = 0.f; accv[n][2] = 0.f;
    }

#pragma unroll
    for (int p = 0; p < 5; ++p) {
#pragma unroll
      for (int hf = 0; hf < 2; ++hf) {
        const int ci = b * 10 + p * 2 + hf;
        // A-frags (global, prefragmented, L2-resident)
        U16x8 a00, a01, a10, a11;
        a00.u = AF[(ci*4 + 0) * 64 + lane];
        a01.u = AF[(ci*4 + 1) * 64 + lane];
        a10.u = AF[(ci*4 + 2) * 64 + lane];
        a11.u = AF[(ci*4 + 3) * 64 + lane];

        // GEMM: C[o(32)][e(64)] = A @ H, C -> sw (bf16)
#pragma unroll
        for (int et = 0; et < 4; ++et) {
          f32x4 c0 = {0.f, 0.f, 0.f, 0.f};
          f32x4 c1 = {0.f, 0.f, 0.f, 0.f};
          c0 = __builtin_amdgcn_mfma_f32_16x16x32_bf16(a00.v, B[et][0], c0, 0, 0, 0);
          c0 = __builtin_amdgcn_mfma_f32_16x16x32_bf16(a01.v, B[et][1], c0, 0, 0, 0);
          c1 = __builtin_amdgcn_mfma_f32_16x16x32_bf16(a10.v, B[et][0], c1, 0, 0, 0);
          c1 = __builtin_amdgcn_mfma_f32_16x16x32_bf16(a11.v, B[et][1], c1, 0, 0, 0);
          unsigned char* wrow = swp + (et*16 + l15) * 80;
          uint2 p0; p0.x = packbf(c0.x, c0.y); p0.y = packbf(c0.z, c0.w);
          uint2 p1; p1.x = packbf(c1.x, c1.y); p1.y = packbf(c1.z, c1.w);
          *(uint2*)(wrow + quad * 8)      = p0;   // o = quad*4 + 0..3
          *(uint2*)(wrow + 32 + quad * 8) = p1;   // o = 16 + quad*4 + 0..3
        }

        // ---- contraction: lane reads its own 32 w values ----
        float wv[32];
        {
          const uint4* wr = (const uint4*)(swp + (size_t)lane * 80);
          uint4 q0 = wr[0], q1 = wr[1], q2 = wr[2], q3 = wr[3];
          unsigned qs_[16] = {q0.x,q0.y,q0.z,q0.w, q1.x,q1.y,q1.z,q1.w,
                              q2.x,q2.y,q2.z,q2.w, q3.x,q3.y,q3.z,q3.w};
#pragma unroll
          for (int i = 0; i < 16; ++i) {
            wv[2*i]   = bflo(qs_[i]);
            wv[2*i+1] = bfhi(qs_[i]);
          }
        }
#pragma unroll
        for (int mm = 0; mm < 4; ++mm) {
          const int m = hf * 4 + mm;
          const float* wm = &wv[mm * 8];
          if (p == 0) {
            float g = xs[m] * s0;
#pragma unroll
            for (int n = 0; n < 8; ++n) accs[n] = fmaf(wm[n], g, accs[n]);
          } else if (p == 1) {
            float a = xs[m];
            float gx = a * s1x, gy = a * s1y, gz = a * s1z;
#pragma unroll
            for (int n = 0; n < 8; ++n) {
              accv[n][0] = fmaf(wm[n], gx, accv[n][0]);
              accv[n][1] = fmaf(wm[n], gy, accv[n][1]);
              accv[n][2] = fmaf(wm[n], gz, accv[n][2]);
            }
          } else if (p == 2) {
            float gx = xv[m][0] * s0, gy = xv[m][1] * s0, gz = xv[m][2] * s0;
#pragma unroll
            for (int n = 0; n < 8; ++n) {
              accv[n][0] = fmaf(wm[n], gx, accv[n][0]);
              accv[n][1] = fmaf(wm[n], gy, accv[n][1]);
              accv[n][2] = fmaf(wm[n], gz, accv[n][2]);
            }
          } else if (p == 3) {
            float dm = (xv[m][0]*s1x + xv[m][1]*s1y + xv[m][2]*s1z) * INV_SQRT3;
#pragma unroll
            for (int n = 0; n < 8; ++n) accs[n] = fmaf(wm[n], dm, accs[n]);
          } else {
            float crx = (xv[m][1]*s1z - xv[m][2]*s1y) * INV_SQRT2;
            float cry = (xv[m][2]*s1x - xv[m][0]*s1z) * INV_SQRT2;
            float crz = (xv[m][0]*s1y - xv[m][1]*s1x) * INV_SQRT2;
#pragma unroll
            for (int n = 0; n < 8; ++n) {
              accv[n][0] = fmaf(wm[n], crx, accv[n][0]);
              accv[n][1] = fmaf(wm[n], cry, accv[n][1]);
              accv[n][2] = fmaf(wm[n], crz, accv[n][2]);
            }
          }
        }
      }
    }

    // ---- epilogue ----
    if (b == 0) {
      float lg = 0.f, lv = 0.f;
#pragma unroll
      for (int n = 0; n < 8; ++n) lg = fmaf(accs[n], qd[dst * 8 + n], lg);
#pragma unroll
      for (int n = 0; n < 8; ++n) {
#pragma unroll
        for (int c = 0; c < 3; ++c)
          lv = fmaf(accv[n][c], qvd[dst * 24 + n * 3 + c], lv);
      }
      float logit = (lg * (1.f / 32.f) +
                     lv * (0.125f * INV_SQRT24) * INV_SQRT3) * 0.25f;
      float ex = __expf(logit);
      if (valid) {
        expo[e] = ex;
        atomicAdd(&z_sum[dst], ex);
        atomicAdd(&cnt[dst], 1.f);
      }
    } else {
      if (valid) {
        float4* v4 = (float4*)(v_edge + (size_t)e * 32);
        float4 o;
        o.x = accs[0] * (1.f/32.f); o.y = accs[1] * (1.f/32.f);
        o.z = accs[2] * (1.f/32.f); o.w = accs[3] * (1.f/32.f);
        v4[0] = o;
        o.x = accs[4] * (1.f/32.f); o.y = accs[5] * (1.f/32.f);
        o.z = accs[6] * (1.f/32.f); o.w = accs[7] * (1.f/32.f);
        v4[1] = o;
        const float sv = 0.125f * INV_SQRT24;
        float vvv[24];
#pragma unroll
        for (int n = 0; n < 8; ++n) {
          vvv[3*n+0] = accv[n][0] * sv;
          vvv[3*n+1] = accv[n][1] * sv;
          vvv[3*n+2] = accv[n][2] * sv;
        }
#pragma unroll
        for (int i = 0; i < 6; ++i) {
          float4 t;
          t.x = vvv[4*i+0]; t.y = vvv[4*i+1]; t.z = vvv[4*i+2]; t.w = vvv[4*i+3];
          v4[2 + i] = t;
        }
      }
    }
  }
}

// ---------------- zinv = max(cnt,1) / z_sum ----------------
__global__ __launch_bounds__(256) void zdiv_kernel(float* __restrict__ z_sum,
                                                   const float* __restrict__ cnt)
{
  int n = blockIdx.x * blockDim.x + threadIdx.x;
  if (n >= NN) return;
  z_sum[n] = fmaxf(cnt[n], 1.f) / z_sum[n];
}

// ---------------- scatter ----------------
__global__ __launch_bounds__(256) void scatter_kernel(
    const int*   __restrict__ edge_index,
    const float* __restrict__ expo,
    const float* __restrict__ zinv,
    const float* __restrict__ v_edge,
    float* __restrict__ out)
{
  int t = blockIdx.x * blockDim.x + threadIdx.x;
  if (t >= NE * 8) return;
  int e = t >> 3;
  int q = t & 7;
  int dst = edge_index[NE + e];
  float a = sqrtf(fmaxf(expo[e] * zinv[dst], 0.f));
  const float4* v4 = (const float4*)v_edge;
  float4 v = v4[e * 8 + q];
  atomicAdd(&out[dst * 32 + q * 4 + 0], a * v.x);
  atomicAdd(&out[dst * 32 + q * 4 + 1], a * v.y);
  atomicAdd(&out[dst * 32 + q * 4 + 2], a * v.z);
  atomicAdd(&out[dst * 32 + q * 4 + 3], a * v.w);
}

extern "C" void kernel_launch(void* const* d_in, const int* in_sizes, int n_in,
                              void* d_out, int out_size, void* d_ws, size_t ws_size,
                              hipStream_t stream)
{
  const float* node_attr  = (const float*)d_in[0];
  const int*   edge_index = (const int*)  d_in[1];
  const float* edge_attr  = (const float*)d_in[2];
  const float* edge_sh    = (const float*)d_in[3];
  const float* Wq0 = (const float*)d_in[4];
  const float* Wq1 = (const float*)d_in[5];
  const float* kW1 = (const float*)d_in[6];
  const float* kW2 = (const float*)d_in[7];
  const float* vW1 = (const float*)d_in[8];
  const float* vW2 = (const float*)d_in[9];
  const float* Wd0 = (const float*)d_in[10];
  const float* Wd1 = (const float*)d_in[11];
  float* out = (float*)d_out;

  float* ws = (float*)d_ws;
  float* qd     = ws;                    // 200000
  float* qvd    = qd   + 200000;         // 600000
  float* kW1T   = qvd  + 600000;         // 1024
  float* vW1T   = kW1T + 1024;           // 1024
  unsigned short* afrag = (unsigned short*)(vW1T + 1024);   // 40960 ushorts
  float* z_sum  = (float*)((char*)afrag + 81920);           // 25024
  float* cnt    = z_sum + 25024;         // 25024
  float* expo   = cnt   + 25024;         // 200000
  float* v_edge = expo  + 200000;        // 6400000

  hipMemsetAsync(out, 0, (size_t)out_size * sizeof(float), stream);
  hipMemsetAsync(z_sum, 0, (size_t)(25024 + 25024) * sizeof(float), stream);

  prep_kernel<<<160, 256, 0, stream>>>(kW1, kW2, vW1, vW2, kW1T, vW1T, afrag);
  node_kernel<<<(NN + 255) / 256, 256, 0, stream>>>(
      node_attr, Wq0, Wq1, Wd0, Wd1, qd, qvd);
  edge_kernel<<<(NE + 255) / 256, 256, 0, stream>>>(
      node_attr, edge_index, edge_attr, edge_sh,
      kW1T, vW1T, afrag, qd, qvd, expo, v_edge, z_sum, cnt);
  zdiv_kernel<<<(NN + 255) / 256, 256, 0, stream>>>(z_sum, cnt);
  scatter_kernel<<<(NE * 8 + 255) / 256, 256, 0, stream>>>(
      edge_index, expo, z_sum, v_edge, out);
}